// Round 9
// baseline (82.009 us; speedup 1.0000x reference)
//
#include <hip/hip_runtime.h>
#include <math.h>

#define C 64
#define IN_DIM 148
#define ODIM 9      // outputs per edge
#define EPT 4       // edges per thread (8 gathers in flight); stores stay PLAIN
// proj row = 9 values, 12-bit fixed point, packed in 16B (aligned, 1 line-piece)
// dequant: v = u/256 - 8   (range +-8, step 1/256, max err 1.95e-3)

typedef _Float16 half_t;
typedef float f4 __attribute__((ext_vector_type(4)));
typedef f4 f4u __attribute__((aligned(4)));
typedef _Float16 h2 __attribute__((ext_vector_type(2)));
typedef unsigned int u32;
typedef u32 u4 __attribute__((ext_vector_type(4)));
typedef int i4 __attribute__((ext_vector_type(4)));

__device__ __forceinline__ float tanh_fast(float x) {
    // tanh(x) = 1 - 2/(e^{2x}+1); saturates correctly at +/-inf
    float e = __expf(2.0f * x);
    return 1.0f - 2.0f / (e + 1.0f);
}

__device__ __forceinline__ void decode9(u4 w, int u[ODIM]) {
    // 12-bit fields at bit offsets 12*i in the 128-bit word
    u[0] = w.x & 0xFFF;
    u[1] = (w.x >> 12) & 0xFFF;
    u[2] = __builtin_amdgcn_alignbit(w.y, w.x, 24) & 0xFFF;
    u[3] = (w.y >> 4) & 0xFFF;
    u[4] = (w.y >> 16) & 0xFFF;
    u[5] = __builtin_amdgcn_alignbit(w.z, w.y, 28) & 0xFFF;
    u[6] = (w.z >> 8) & 0xFFF;
    u[7] = (w.z >> 20) & 0xFFF;
    u[8] = w.w & 0xFFF;
}

// ---------------- node projection kernel: 2 threads per node (src/dst half) --
__global__ __launch_bounds__(256) void node_proj_kernel(
    const float* __restrict__ x, const int* __restrict__ node_types,
    const float* __restrict__ W, u4* __restrict__ sp, u4* __restrict__ dp,
    int N)
{
    __shared__ _Float16 Wh[2 * ODIM][C];   // r<9: W[r][c]; r>=9: W[r-9][64+c]  (fp16)
    __shared__ float ntab[2][ODIM][4];     // [0]=src-type consts, [1]=dst-type consts

    for (int i = threadIdx.x; i < 2 * ODIM * C; i += 256) {
        int r = i >> 6, c = i & 63;
        int o = (r < ODIM) ? r : r - ODIM;
        int col = (r < ODIM) ? c : (C + c);
        Wh[r][c] = (_Float16)W[o * IN_DIM + col];
    }
    for (int i = threadIdx.x; i < 2 * ODIM * 4; i += 256) {
        int t = i & 3;
        int o = (i >> 2) % ODIM;
        int sd = (i >> 2) / ODIM;
        ntab[sd][o][t] = W[o * IN_DIM + 128 + sd * 4 + t];
    }
    __syncthreads();

    int tid = blockIdx.x * 256 + threadIdx.x;
    int n = tid >> 1;
    int h = tid & 1;                     // 0 = src half, 1 = dst half
    if (n >= N) return;

    const f4* xr = (const f4*)(x + (size_t)n * C);
    h2 xh[32];
#pragma unroll
    for (int q = 0; q < 16; ++q) {
        f4 v = xr[q];
        xh[2 * q]     = h2{(_Float16)v.x, (_Float16)v.y};
        xh[2 * q + 1] = h2{(_Float16)v.z, (_Float16)v.w};
    }

    float acc[ODIM];
#pragma unroll
    for (int o = 0; o < ODIM; ++o) acc[o] = 0.0f;

#pragma unroll
    for (int g = 0; g < 8; ++g) {          // 8 halfs (16B) per group
#pragma unroll
        for (int o = 0; o < ODIM; ++o) {
            const h2* wp = (const h2*)&Wh[h * ODIM + o][g * 8];  // ds_read_b128
            acc[o] = __builtin_amdgcn_fdot2(xh[4 * g + 0], wp[0], acc[o], false);
            acc[o] = __builtin_amdgcn_fdot2(xh[4 * g + 1], wp[1], acc[o], false);
            acc[o] = __builtin_amdgcn_fdot2(xh[4 * g + 2], wp[2], acc[o], false);
            acc[o] = __builtin_amdgcn_fdot2(xh[4 * g + 3], wp[3], acc[o], false);
        }
    }

    int t = node_types[n];
    u32 u[ODIM];
#pragma unroll
    for (int o = 0; o < ODIM; ++o) {
        float v = acc[o] + ntab[h][o][t];
        int q = (int)rintf(fmaf(v, 256.0f, 2048.0f));   // (v+8)*256
        q = q < 0 ? 0 : (q > 4095 ? 4095 : q);
        u[o] = (u32)q;
    }
    u4 w;
    w.x = u[0] | (u[1] << 12) | (u[2] << 24);
    w.y = (u[2] >> 8) | (u[3] << 4) | (u[4] << 16) | (u[5] << 28);
    w.z = (u[5] >> 4) | (u[6] << 8) | (u[7] << 20);
    w.w = u[8];

    (h ? dp : sp)[n] = w;                // one 16B aligned store
}

// ------- edge kernel: EPT=4, 8 gathers in flight, PLAIN stores --------------
__global__ __launch_bounds__(256) void edge_kernel(
    const int* __restrict__ ei, const int* __restrict__ etypes,
    const u4* __restrict__ sp, const u4* __restrict__ dp,
    const float* __restrict__ W, float* __restrict__ out,
    int E)
{
    __shared__ float etab2[12][ODIM];    // etab2[t][o] = W[o][136+t] - 16 (folds dequant offsets)
    for (int i = threadIdx.x; i < 12 * ODIM; i += 256) {
        int t = i / ODIM, o = i - t * ODIM;
        etab2[t][o] = W[o * IN_DIM + 136 + t] - 16.0f;
    }
    __syncthreads();

    int tid = blockIdx.x * 256 + threadIdx.x;
    int e0 = tid * EPT;
    if (e0 >= E) return;

    i4 s4, d4, t4;
    if (e0 + EPT <= E) {
        // streaming, nt: don't evict the L2-resident proj set
        s4 = __builtin_nontemporal_load((const i4*)(ei + e0));
        d4 = __builtin_nontemporal_load((const i4*)(ei + (size_t)E + e0));
        t4 = __builtin_nontemporal_load((const i4*)(etypes + e0));
    } else {
#pragma unroll
        for (int k = 0; k < EPT; ++k) {
            int e = e0 + k; if (e > E - 1) e = E - 1;
            s4[k] = ei[e]; d4[k] = ei[(size_t)E + e]; t4[k] = etypes[e];
        }
    }

    // 8 independent 16B gathers, all issued before first use
    u4 sw[EPT], dw[EPT];
#pragma unroll
    for (int k = 0; k < EPT; ++k) sw[k] = sp[s4[k]];
#pragma unroll
    for (int k = 0; k < EPT; ++k) dw[k] = dp[d4[k]];

#pragma unroll
    for (int k = 0; k < EPT; ++k) {
        int e = e0 + k;
        if (e >= E) break;
        int us[ODIM], ud[ODIM];
        decode9(sw[k], us);
        decode9(dw[k], ud);
        const float* eb = &etab2[t4[k]][0];
        float r[ODIM];
#pragma unroll
        for (int o = 0; o < ODIM; ++o)
            r[o] = tanh_fast(fmaf((float)(us[o] + ud[o]), 1.0f / 256.0f, eb[o]));

        // PLAIN stores: partial lines merge in L2 (nt stores -> 3.3x WRITE, R6)
        float* op = out + (size_t)e * ODIM;
        f4 v0 = {r[0], r[1], r[2], r[3]};
        f4 v1 = {r[4], r[5], r[6], r[7]};
        *(f4u*)op = v0;
        *(f4u*)(op + 4) = v1;
        op[8] = r[8];
    }
}

extern "C" void kernel_launch(void* const* d_in, const int* in_sizes, int n_in,
                              void* d_out, int out_size, void* d_ws, size_t ws_size,
                              hipStream_t stream) {
    const float* x      = (const float*)d_in[0];
    const int*   ei     = (const int*)d_in[1];
    const int*   etypes = (const int*)d_in[2];
    const int*   ntypes = (const int*)d_in[3];
    const float* W      = (const float*)d_in[4];
    float* out = (float*)d_out;

    int N = in_sizes[0] / C;    // 100000
    int E = in_sizes[2];        // 1600000

    u4* sp = (u4*)d_ws;                  // N x 16B
    u4* dp = sp + N;                     // N x 16B  (total 3.2 MB)

    int nthreads = N * 2;
    int nblocks  = (nthreads + 255) / 256;
    node_proj_kernel<<<nblocks, 256, 0, stream>>>(x, ntypes, W, sp, dp, N);

    int ethreads = (E + EPT - 1) / EPT;
    int eblocks  = (ethreads + 255) / 256;
    edge_kernel<<<eblocks, 256, 0, stream>>>(ei, etypes, sp, dp, W, out, E);
}

// Round 10
// 44.055 us; speedup vs baseline: 1.8615x; 1.8615x over previous
//
#include <hip/hip_runtime.h>
#include <math.h>

#define C 64
#define IN_DIM 148
#define ODIM 9      // outputs per edge
// proj row = 9 values, 12-bit fixed point, packed in 16B (aligned, 1 line-piece)
// dequant: v = u/256 - 8   (range +-8, step 1/256, max err 1.95e-3)

typedef _Float16 half_t;
typedef float f4 __attribute__((ext_vector_type(4)));
typedef _Float16 h2 __attribute__((ext_vector_type(2)));
typedef unsigned int u32;
typedef u32 u4 __attribute__((ext_vector_type(4)));

__device__ __forceinline__ float tanh_fast(float x) {
    // tanh(x) = 1 - 2/(e^{2x}+1); saturates correctly at +/-inf
    float e = __expf(2.0f * x);
    return 1.0f - 2.0f / (e + 1.0f);
}

__device__ __forceinline__ void decode9(u4 w, int u[ODIM]) {
    // 12-bit fields at bit offsets 12*i in the 128-bit word
    u[0] = w.x & 0xFFF;
    u[1] = (w.x >> 12) & 0xFFF;
    u[2] = __builtin_amdgcn_alignbit(w.y, w.x, 24) & 0xFFF;
    u[3] = (w.y >> 4) & 0xFFF;
    u[4] = (w.y >> 16) & 0xFFF;
    u[5] = __builtin_amdgcn_alignbit(w.z, w.y, 28) & 0xFFF;
    u[6] = (w.z >> 8) & 0xFFF;
    u[7] = (w.z >> 20) & 0xFFF;
    u[8] = w.w & 0xFFF;
}

// ---------------- node projection kernel: 2 threads per node (src/dst half) --
__global__ __launch_bounds__(256) void node_proj_kernel(
    const float* __restrict__ x, const int* __restrict__ node_types,
    const float* __restrict__ W, u4* __restrict__ sp, u4* __restrict__ dp,
    int N)
{
    __shared__ _Float16 Wh[2 * ODIM][C];   // r<9: W[r][c]; r>=9: W[r-9][64+c]  (fp16)
    __shared__ float ntab[2][ODIM][4];     // [0]=src-type consts, [1]=dst-type consts

    for (int i = threadIdx.x; i < 2 * ODIM * C; i += 256) {
        int r = i >> 6, c = i & 63;
        int o = (r < ODIM) ? r : r - ODIM;
        int col = (r < ODIM) ? c : (C + c);
        Wh[r][c] = (_Float16)W[o * IN_DIM + col];
    }
    for (int i = threadIdx.x; i < 2 * ODIM * 4; i += 256) {
        int t = i & 3;
        int o = (i >> 2) % ODIM;
        int sd = (i >> 2) / ODIM;
        ntab[sd][o][t] = W[o * IN_DIM + 128 + sd * 4 + t];
    }
    __syncthreads();

    int tid = blockIdx.x * 256 + threadIdx.x;
    int n = tid >> 1;
    int h = tid & 1;                     // 0 = src half, 1 = dst half
    if (n >= N) return;

    const f4* xr = (const f4*)(x + (size_t)n * C);
    h2 xh[32];
#pragma unroll
    for (int q = 0; q < 16; ++q) {
        f4 v = xr[q];
        xh[2 * q]     = h2{(_Float16)v.x, (_Float16)v.y};
        xh[2 * q + 1] = h2{(_Float16)v.z, (_Float16)v.w};
    }

    float acc[ODIM];
#pragma unroll
    for (int o = 0; o < ODIM; ++o) acc[o] = 0.0f;

#pragma unroll
    for (int g = 0; g < 8; ++g) {          // 8 halfs (16B) per group
#pragma unroll
        for (int o = 0; o < ODIM; ++o) {
            const h2* wp = (const h2*)&Wh[h * ODIM + o][g * 8];  // ds_read_b128
            acc[o] = __builtin_amdgcn_fdot2(xh[4 * g + 0], wp[0], acc[o], false);
            acc[o] = __builtin_amdgcn_fdot2(xh[4 * g + 1], wp[1], acc[o], false);
            acc[o] = __builtin_amdgcn_fdot2(xh[4 * g + 2], wp[2], acc[o], false);
            acc[o] = __builtin_amdgcn_fdot2(xh[4 * g + 3], wp[3], acc[o], false);
        }
    }

    int t = node_types[n];
    u32 u[ODIM];
#pragma unroll
    for (int o = 0; o < ODIM; ++o) {
        float v = acc[o] + ntab[h][o][t];
        int q = (int)rintf(fmaf(v, 256.0f, 2048.0f));   // (v+8)*256
        q = q < 0 ? 0 : (q > 4095 ? 4095 : q);
        u[o] = (u32)q;
    }
    u4 w;
    w.x = u[0] | (u[1] << 12) | (u[2] << 24);
    w.y = (u[2] >> 8) | (u[3] << 4) | (u[4] << 16) | (u[5] << 28);
    w.z = (u[5] >> 4) | (u[6] << 8) | (u[7] << 20);
    w.w = u[8];

    (h ? dp : sp)[n] = w;                // one 16B aligned store
}

// ---- edge kernel: 1 edge/thread, LDS-staged fully-dense NT output stores ----
__global__ __launch_bounds__(256) void edge_kernel(
    const int* __restrict__ ei, const int* __restrict__ etypes,
    const u4* __restrict__ sp, const u4* __restrict__ dp,
    const float* __restrict__ W, float* __restrict__ out,
    int E)
{
    __shared__ float etab2[12][ODIM];    // etab2[t][o] = W[o][136+t] - 16 (folds dequant offsets)
    __shared__ alignas(16) float sm[256 * ODIM];   // 9216 B staging

    for (int i = threadIdx.x; i < 12 * ODIM; i += 256) {
        int t = i / ODIM, o = i - t * ODIM;
        etab2[t][o] = W[o * IN_DIM + 136 + t] - 16.0f;
    }
    __syncthreads();

    int base = blockIdx.x * 256;
    int e = base + threadIdx.x;
    int cnt = E - base; if (cnt > 256) cnt = 256;

    if (threadIdx.x < cnt) {
        // streaming index loads: non-temporal, don't evict the L2-resident proj set
        int s  = __builtin_nontemporal_load(ei + e);
        int d  = __builtin_nontemporal_load(ei + (size_t)E + e);
        int et = __builtin_nontemporal_load(etypes + e);

        // exactly 2 random 16B gathers (target: local-XCD L2 hits)
        u4 sw = sp[s];
        u4 dw = dp[d];

        int us[ODIM], ud[ODIM];
        decode9(sw, us);
        decode9(dw, ud);

        const float* eb = &etab2[et][0];
#pragma unroll
        for (int o = 0; o < ODIM; ++o) {
            float v = fmaf((float)(us[o] + ud[o]), 1.0f / 256.0f, eb[o]);
            sm[threadIdx.x * ODIM + o] = tanh_fast(v);
        }
    }
    __syncthreads();

    // fully line-dense output: each nt store instruction = 64 lanes x 16B
    // contiguous = 16 whole 64B lines -> streams to HBM, zero L2 pollution,
    // zero partial-line RFO (R6/R9 lesson).
    float* ob = out + (size_t)base * ODIM;   // 9216B-aligned
    if (cnt == 256) {
        const f4* smv = (const f4*)sm;
        f4* obv = (f4*)ob;
#pragma unroll
        for (int j = threadIdx.x; j < 256 * ODIM / 4; j += 256)
            __builtin_nontemporal_store(smv[j], obv + j);
    } else {
        int tot = cnt * ODIM;
        for (int j = threadIdx.x; j < tot; j += 256)
            __builtin_nontemporal_store(sm[j], ob + j);
    }
}

extern "C" void kernel_launch(void* const* d_in, const int* in_sizes, int n_in,
                              void* d_out, int out_size, void* d_ws, size_t ws_size,
                              hipStream_t stream) {
    const float* x      = (const float*)d_in[0];
    const int*   ei     = (const int*)d_in[1];
    const int*   etypes = (const int*)d_in[2];
    const int*   ntypes = (const int*)d_in[3];
    const float* W      = (const float*)d_in[4];
    float* out = (float*)d_out;

    int N = in_sizes[0] / C;    // 100000
    int E = in_sizes[2];        // 1600000

    u4* sp = (u4*)d_ws;                  // N x 16B
    u4* dp = sp + N;                     // N x 16B  (total 3.2 MB)

    int nthreads = N * 2;
    int nblocks  = (nthreads + 255) / 256;
    node_proj_kernel<<<nblocks, 256, 0, stream>>>(x, ntypes, W, sp, dp, N);

    int eblocks = (E + 255) / 256;
    edge_kernel<<<eblocks, 256, 0, stream>>>(ei, etypes, sp, dp, W, out, E);
}